// Round 20
// baseline (3461.940 us; speedup 1.0000x reference)
//
#include <hip/hip_runtime.h>
#include <math.h>

// B=32, L=1024, D=256, G=768
#define NROWS 32768  // B*L

typedef float v4 __attribute__((ext_vector_type(4)));
typedef _Float16 h2 __attribute__((ext_vector_type(2)));
typedef _Float16 f16x8 __attribute__((ext_vector_type(8)));
typedef float f32x4 __attribute__((ext_vector_type(4)));

__device__ __forceinline__ float geluf(float x){ return 0.5f*x*(1.0f+erff(x*0.70710678118654752f)); }

__device__ __forceinline__ float fexp2(float x){
#if __has_builtin(__builtin_amdgcn_exp2f)
    return __builtin_amdgcn_exp2f(x);
#else
    return exp2f(x);
#endif
}
__device__ __forceinline__ float frcp(float x){
#if __has_builtin(__builtin_amdgcn_rcpf)
    return __builtin_amdgcn_rcpf(x);
#else
    return 1.0f/x;
#endif
}
#define LOG2E 1.44269504088896f
__device__ __forceinline__ float fexp(float x){ return fexp2(x*LOG2E); }
__device__ __forceinline__ float sigm(float x){ return frcp(1.0f + fexp2(-LOG2E*x)); }
__device__ __forceinline__ float ftanh(float x){ return 1.0f - 2.0f*frcp(fexp2(2.0f*LOG2E*x) + 1.0f); }

__device__ __forceinline__ float dot2(h2 a, h2 b, float c){
#if __has_builtin(__builtin_amdgcn_fdot2)
    return __builtin_amdgcn_fdot2(a, b, c, false);
#else
    return c + (float)a.x*(float)b.x + (float)a.y*(float)b.y;
#endif
}
__device__ __forceinline__ h2 cvt2(float2 a){ return h2{(_Float16)a.x, (_Float16)a.y}; }

// barrier that does NOT drain vmcnt: LDS visibility only.
__device__ __forceinline__ void wg_barrier(){
    asm volatile("s_waitcnt lgkmcnt(0)" ::: "memory");
    __builtin_amdgcn_s_barrier();
    __builtin_amdgcn_sched_barrier(0);
}

// ---------------- start embed: sh[b,d] ----------------
__global__ __launch_bounds__(256) void k_start_embed(
    const float* __restrict__ ne, const float* __restrict__ w0, const float* __restrict__ b0,
    const float* __restrict__ w1, const float* __restrict__ b1,
    const float* __restrict__ w2, const float* __restrict__ b2,
    float* __restrict__ sh)
{
    __shared__ __align__(16) float encL[1024];
    __shared__ __align__(16) float g1[256];
    __shared__ __align__(16) float g2[256];
    int b = blockIdx.x, t = threadIdx.x;
    for (int i = t; i < 1024; i += 256) encL[i] = ne[b*1024 + i];
    __syncthreads();
    const float4* wr = (const float4*)(w0 + (size_t)t*1024);
    const float4* e4 = (const float4*)encL;
    float a0=0,a1=0,a2=0,a3=0;
    #pragma unroll 8
    for (int k = 0; k < 256; ++k){ float4 w = wr[k], e = e4[k];
        a0 += w.x*e.x; a1 += w.y*e.y; a2 += w.z*e.z; a3 += w.w*e.w; }
    float t1 = a0+a1+a2+a3 + b0[t];
    float res = t1;
    g1[t] = geluf(t1);
    __syncthreads();
    const float4* w1r = (const float4*)(w1 + (size_t)t*256);
    const float4* g14 = (const float4*)g1;
    a0=a1=a2=a3=0.f;
    #pragma unroll 8
    for (int k = 0; k < 64; ++k){ float4 w = w1r[k], e = g14[k];
        a0 += w.x*e.x; a1 += w.y*e.y; a2 += w.z*e.z; a3 += w.w*e.w; }
    g2[t] = geluf(a0+a1+a2+a3 + b1[t]);
    __syncthreads();
    const float4* w2r = (const float4*)(w2 + (size_t)t*256);
    const float4* g24 = (const float4*)g2;
    a0=a1=a2=a3=0.f;
    #pragma unroll 8
    for (int k = 0; k < 64; ++k){ float4 w = w2r[k], e = g24[k];
        a0 += w.x*e.x; a1 += w.y*e.y; a2 += w.z*e.z; a3 += w.w*e.w; }
    sh[b*256 + t] = a0+a1+a2+a3 + b2[t] + res;
}

// hperm: dim = (hi:2)(mid:3)(lo:3) -> idx = mid*32 + hi*8 + lo (bijective).
__device__ __forceinline__ int hperm(int dim){
    return ((dim >> 3) & 7)*32 + ((dim >> 6) << 3) + (dim & 7);
}

__global__ __launch_bounds__(64) void k_zero(unsigned* flags){
    flags[threadIdx.x] = 0u;
}

// ---------------- fused pipeline: scan0 | xp-matvec | scan1 on 96 CUs ----------------
// role = blockIdx/32: 0 = GRU layer0 (produces o0, flagsA), 1 = xp = W_ih1.o0[l]
// (consumes flagsA, produces xpf + flagsB), 2 = GRU layer1 (consumes flagsB).
// Chunked (8-step) device-scope flag sync: producer chunk-end does
// syncthreads (vmcnt drain) + threadfence (L2 writeback) + atomicExch (coherent
// RMW); consumer chunk-top spin-polls atomicAdd(flag,0) + threadfence (inv).
// Weights are register/LDS-resident -> immune to the invalidates. All 96 WGs
// co-resident (133KB LDS -> 1/CU); producers never wait -> no deadlock; poll
// capped so a sync bug fails cleanly instead of hanging.
__global__ __launch_bounds__(512) void k_pipe(
    const float* __restrict__ w_hh0, const float* __restrict__ b_hh0,
    const float* __restrict__ w_ih0, const float* __restrict__ b_ih0,
    const float* __restrict__ w_hh1, const float* __restrict__ b_hh1,
    const float* __restrict__ w_ih1v, const float* __restrict__ b_ih1,
    const int*   __restrict__ trg, const float* __restrict__ sh,
    float* __restrict__ o0, _Float16* __restrict__ xpf,
    float* __restrict__ outs, unsigned* __restrict__ flags)
{
    __shared__ __align__(16) float4 wNs[8192];      // 128KB
    __shared__ __align__(16) _Float16 hbuf[2][256];
    __shared__ __align__(16) float bitL[1024];      // role0: bits; role1: obuf (8x256 f16)
    int role = blockIdx.x >> 5, b = blockIdx.x & 31, t = threadIdx.x;
    int d = t >> 1, half = t & 1;

    if (role == 1) {
        // ======== stage 2: xp[l] = W_ih1 . o0[l] + b_ih1 ========
        {   // wN rows of w_ih1 -> LDS
            const float2* src = (const float2*)(w_ih1v + (size_t)(512 + d)*256 + half*128);
            #pragma unroll
            for (int kk = 0; kk < 16; ++kk) {
                h2 p0 = cvt2(src[kk*4+0]), p1 = cvt2(src[kk*4+1]);
                h2 p2 = cvt2(src[kk*4+2]), p3 = cvt2(src[kk*4+3]);
                float4 v;
                v.x = __builtin_bit_cast(float, p0); v.y = __builtin_bit_cast(float, p1);
                v.z = __builtin_bit_cast(float, p2); v.w = __builtin_bit_cast(float, p3);
                wNs[kk*512 + t] = v;
            }
        }
        h2 wR[64], wZ[64];
        {
            const float2* wr = (const float2*)(w_ih1v + (size_t)d*256       + half*128);
            const float2* wz = (const float2*)(w_ih1v + (size_t)(d+256)*256 + half*128);
            #pragma unroll
            for (int k = 0; k < 64; ++k) { wR[k] = cvt2(wr[k]); wZ[k] = cvt2(wz[k]); }
        }
        float bir = b_ih1[d], biz = b_ih1[256 + d], bin = b_ih1[512 + d];
        _Float16* obuf = (_Float16*)bitL;   // 8 rows x 256 f16 (hperm layout)
        __syncthreads();

        for (int lc0 = 0; lc0 < 1024; lc0 += 8) {
            if (t == 0) {
                unsigned tgt = (unsigned)(lc0 + 8);
                for (long it = 0; it < 10000000L; ++it) {
                    if (atomicAdd(&flags[b], 0u) >= tgt) break;
                    __builtin_amdgcn_s_sleep(2);
                }
            }
            __syncthreads(); __threadfence(); __syncthreads();
            {   // stage 8 rows of o0 -> obuf (f16, hperm)
                int r = t >> 6, c4 = t & 63;
                float4 v = *(const float4*)(o0 + ((size_t)(lc0 + r)*32 + b)*256 + c4*4);
                h2 pa; pa[0] = (_Float16)v.x; pa[1] = (_Float16)v.y;
                h2 pb; pb[0] = (_Float16)v.z; pb[1] = (_Float16)v.w;
                *(float2*)(&obuf[r*256 + hperm(c4*4)]) = make_float2(
                    __builtin_bit_cast(float, pa), __builtin_bit_cast(float, pb));
            }
            wg_barrier();
            #pragma unroll 2
            for (int r = 0; r < 8; ++r) {
                int ls = lc0 + r;
                const float4* hb4 = (const float4*)(&obuf[r*256]);
                float ar = 0.f, az = 0.f, an = 0.f;
                #pragma unroll
                for (int kk = 0; kk < 16; ++kk) {
                    float4 hv = hb4[(kk & 7)*4 + half*2 + (kk >> 3)];
                    float4 wv = wNs[kk*512 + t];
                    h2 h0 = __builtin_bit_cast(h2, hv.x);
                    h2 h1 = __builtin_bit_cast(h2, hv.y);
                    h2 hc = __builtin_bit_cast(h2, hv.z);
                    h2 h3 = __builtin_bit_cast(h2, hv.w);
                    ar = dot2(wR[4*kk+0], h0, ar); ar = dot2(wR[4*kk+1], h1, ar);
                    ar = dot2(wR[4*kk+2], hc, ar); ar = dot2(wR[4*kk+3], h3, ar);
                    az = dot2(wZ[4*kk+0], h0, az); az = dot2(wZ[4*kk+1], h1, az);
                    az = dot2(wZ[4*kk+2], hc, az); az = dot2(wZ[4*kk+3], h3, az);
                    an = dot2(__builtin_bit_cast(h2, wv.x), h0, an);
                    an = dot2(__builtin_bit_cast(h2, wv.y), h1, an);
                    an = dot2(__builtin_bit_cast(h2, wv.z), hc, an);
                    an = dot2(__builtin_bit_cast(h2, wv.w), h3, an);
                }
                ar += __shfl_xor(ar, 1);
                az += __shfl_xor(az, 1);
                an += __shfl_xor(an, 1);
                if (half) {
                    size_t base = ((size_t)ls*32 + b)*768;
                    xpf[base + d]       = (_Float16)(ar + bir);
                    xpf[base + 256 + d] = (_Float16)(az + biz);
                    xpf[base + 512 + d] = (_Float16)(an + bin);
                }
            }
            __syncthreads(); __threadfence(); __syncthreads();
            if (t == 0) atomicExch(&flags[32 + b], (unsigned)(lc0 + 8));
        }
        return;
    }

    // ======== roles 0 / 2: GRU scan (v12 structure) ========
    const float* w_hh = (role == 0) ? w_hh0 : w_hh1;
    const float* b_hh = (role == 0) ? b_hh0 : b_hh1;
    if (role == 0)
        #pragma unroll
        for (int i = 0; i < 2; ++i) {
            int idx = t + i*512;
            bitL[idx] = (idx == 0) ? 1.0f : (float)trg[b*1024 + idx - 1];
        }
    {
        const float2* src = (const float2*)(w_hh + (size_t)(512 + d)*256 + half*128);
        #pragma unroll
        for (int kk = 0; kk < 16; ++kk) {
            h2 p0 = cvt2(src[kk*4+0]), p1 = cvt2(src[kk*4+1]);
            h2 p2 = cvt2(src[kk*4+2]), p3 = cvt2(src[kk*4+3]);
            float4 v;
            v.x = __builtin_bit_cast(float, p0); v.y = __builtin_bit_cast(float, p1);
            v.z = __builtin_bit_cast(float, p2); v.w = __builtin_bit_cast(float, p3);
            wNs[kk*512 + t] = v;
        }
    }
    h2 wR[64], wZ[64];
    {
        const float2* wr = (const float2*)(w_hh + (size_t)d*256       + half*128);
        const float2* wz = (const float2*)(w_hh + (size_t)(d+256)*256 + half*128);
        #pragma unroll
        for (int k = 0; k < 64; ++k) { wR[k] = cvt2(wr[k]); wZ[k] = cvt2(wz[k]); }
    }
    float bhr = b_hh[d], bhz = b_hh[256 + d], bhn = b_hh[512 + d];
    float wir=0.f, wiz=0.f, win=0.f, bir=0.f, biz=0.f, bin=0.f;
    if (role == 0) {
        wir = w_ih0[d]; wiz = w_ih0[256 + d]; win = w_ih0[512 + d];
        bir = b_ih0[d]; biz = b_ih0[256 + d]; bin = b_ih0[512 + d];
    }
    float hreg = sh[b*256 + d];
    if (half == 0) hbuf[0][hperm(d)] = (_Float16)hreg;
    __syncthreads();

    for (int l = 0; l < 1024; ++l) {
        float xr = 0.f, xz = 0.f, xn = 0.f;
        if (role == 2) {
            if ((l & 7) == 0) {
                if (t == 0) {
                    unsigned tgt = (unsigned)(l + 8);
                    for (long it = 0; it < 10000000L; ++it) {
                        if (atomicAdd(&flags[32 + b], 0u) >= tgt) break;
                        __builtin_amdgcn_s_sleep(2);
                    }
                }
                __syncthreads(); __threadfence(); __syncthreads();
            }
            size_t base = ((size_t)l*32 + b)*768;
            xr = (float)xpf[base + d]; xz = (float)xpf[base + 256 + d]; xn = (float)xpf[base + 512 + d];
        }
        const float4* hb4 = (const float4*)(&hbuf[l & 1][0]);
        float ar = 0.f, az = 0.f, an = 0.f;
        #pragma unroll
        for (int kk = 0; kk < 16; ++kk) {
            float4 hv = hb4[(kk & 7)*4 + half*2 + (kk >> 3)];
            float4 wv = wNs[kk*512 + t];
            h2 h0 = __builtin_bit_cast(h2, hv.x);
            h2 h1 = __builtin_bit_cast(h2, hv.y);
            h2 hc = __builtin_bit_cast(h2, hv.z);
            h2 h3 = __builtin_bit_cast(h2, hv.w);
            ar = dot2(wR[4*kk+0], h0, ar); ar = dot2(wR[4*kk+1], h1, ar);
            ar = dot2(wR[4*kk+2], hc, ar); ar = dot2(wR[4*kk+3], h3, ar);
            az = dot2(wZ[4*kk+0], h0, az); az = dot2(wZ[4*kk+1], h1, az);
            az = dot2(wZ[4*kk+2], hc, az); az = dot2(wZ[4*kk+3], h3, az);
            an = dot2(__builtin_bit_cast(h2, wv.x), h0, an);
            an = dot2(__builtin_bit_cast(h2, wv.y), h1, an);
            an = dot2(__builtin_bit_cast(h2, wv.z), hc, an);
            an = dot2(__builtin_bit_cast(h2, wv.w), h3, an);
        }
        ar += __shfl_xor(ar, 1);
        az += __shfl_xor(az, 1);
        an += __shfl_xor(an, 1);
        if (role == 0) {
            float bit = bitL[l];
            xr = bir + bit*wir; xz = biz + bit*wiz; xn = bin + bit*win;
        }
        float r = sigm(xr + ar + bhr);
        float z = sigm(xz + az + bhz);
        float n = ftanh(xn + r*(an + bhn));
        hreg = (1.0f - z)*n + z*hreg;
        if (half == 0) {
            hbuf[(l + 1) & 1][hperm(d)] = (_Float16)hreg;
        } else {
            size_t oidx = (role == 0) ? (((size_t)l*32 + b)*256 + d)
                                      : (((size_t)b*1024 + l)*256 + d);
            float* dst = (role == 0) ? o0 : outs;
            dst[oidx] = hreg;
        }
        if (role == 0 && (l & 7) == 7) {
            __syncthreads(); __threadfence(); __syncthreads();
            if (t == 0) atomicExch(&flags[b], (unsigned)(l + 1));
        } else {
            wg_barrier();
        }
    }
}

// ---------------- f16 MFMA GEMM (R9-verified; optional f16 output) ----------------
__global__ __launch_bounds__(256, 3) void k_gemm_mfma(
    const float* __restrict__ A, const float* __restrict__ B,
    const float* __restrict__ bias, float* __restrict__ C,
    int M, int N, int K, int act, int aMode, int outHalf,
    const float* __restrict__ A1, const float* __restrict__ A2)
{
    __shared__ __align__(16) _Float16 As[128][40];
    __shared__ __align__(16) _Float16 Bs[128][40];
    int nbn = N >> 7;
    int bx = blockIdx.x % nbn, by = blockIdx.x / nbn;
    int m0 = by << 7, n0 = bx << 7;
    int t = threadIdx.x;
    int w = t >> 6, l = t & 63;
    int wm = w >> 1, wn = w & 1;
    int lc = l & 15, lg = l >> 4;
    f32x4 acc[4][4] = {};
    for (int kt = 0; kt < K; kt += 32) {
        __syncthreads();
        #pragma unroll
        for (int p = 0; p < 4; ++p) {
            int slot = t + p*256;
            int m = slot >> 3, kc = slot & 7;
            int gk = kt + kc*4;
            float4 va;
            if (aMode == 0) {
                va = *(const float4*)(A + (size_t)(m0+m)*K + gk);
            } else {
                int part = gk >> 8, kk = gk & 255;
                const float* P = (part == 0) ? A : ((part == 1) ? A1 : A2);
                int row = (part == 2) ? ((m0+m) >> 10) : (m0+m);
                va = *(const float4*)(P + (size_t)row*256 + kk);
            }
            h2 pa; pa[0] = (_Float16)va.x; pa[1] = (_Float16)va.y;
            h2 pb; pb[0] = (_Float16)va.z; pb[1] = (_Float16)va.w;
            *(float2*)(&As[m][kc*4]) = make_float2(__builtin_bit_cast(float, pa),
                                                   __builtin_bit_cast(float, pb));
            float4 vb = *(const float4*)(B + (size_t)(n0+m)*K + gk);
            h2 qa; qa[0] = (_Float16)vb.x; qa[1] = (_Float16)vb.y;
            h2 qb; qb[0] = (_Float16)vb.z; qb[1] = (_Float16)vb.w;
            *(float2*)(&Bs[m][kc*4]) = make_float2(__builtin_bit_cast(float, qa),
                                                   __builtin_bit_cast(float, qb));
        }
        __syncthreads();
        f16x8 af[4], bf[4];
        #pragma unroll
        for (int mt = 0; mt < 4; ++mt)
            af[mt] = *(const f16x8*)(&As[wm*64 + mt*16 + lc][lg*8]);
        #pragma unroll
        for (int nt = 0; nt < 4; ++nt)
            bf[nt] = *(const f16x8*)(&Bs[wn*64 + nt*16 + lc][lg*8]);
        #pragma unroll
        for (int mt = 0; mt < 4; ++mt)
            #pragma unroll
            for (int nt = 0; nt < 4; ++nt)
                acc[mt][nt] = __builtin_amdgcn_mfma_f32_16x16x32_f16(af[mt], bf[nt], acc[mt][nt], 0, 0, 0);
    }
    #pragma unroll
    for (int nt = 0; nt < 4; ++nt) {
        int col = n0 + wn*64 + nt*16 + lc;
        float bv = bias[col];
        #pragma unroll
        for (int mt = 0; mt < 4; ++mt) {
            int rbase = m0 + wm*64 + mt*16 + lg*4;
            #pragma unroll
            for (int r = 0; r < 4; ++r) {
                float v = acc[mt][nt][r] + bv;
                if (act == 1) v = geluf(v);
                else if (act == 2) v = ftanh(v);
                if (outHalf) ((_Float16*)C)[(size_t)(rbase + r)*N + col] = (_Float16)v;
                else         C[(size_t)(rbase + r)*N + col] = v;
            }
        }
    }
}

// ---------------- MFMA flash attention v5 (R17-R19-passing) ----------------
__global__ __launch_bounds__(256) void k_attn_mfma(
    const float* __restrict__ outs, const float* __restrict__ modif, float* __restrict__ ctx)
{
    __shared__ __align__(16) _Float16 Qsh[64][264];
    __shared__ __align__(16) _Float16 Qsl[64][264];
    __shared__ __align__(16) _Float16 Ksh[32][264];
    __shared__ __align__(16) _Float16 Ksl[32][264];
    __shared__ __align__(16) _Float16 Vt[256][40];
    __shared__ __align__(16) _Float16 sP[4][16][40];
    int b = blockIdx.y, bx = blockIdx.x, l0 = bx << 6, t = threadIdx.x;
    int w = t >> 6, l = t & 63;
    int lc = l & 15, lg = l >> 4;

    #pragma unroll
    for (int p = 0; p < 16; ++p) {
        int i = p*256 + t;
        int row = i >> 6, c4 = i & 63;
        float4 v = *(const float4*)(outs + ((size_t)b*1024 + l0 + row)*256 + c4*4);
        _Float16 hx = (_Float16)v.x, hy = (_Float16)v.y, hz = (_Float16)v.z, hw = (_Float16)v.w;
        h2 pa; pa[0] = hx; pa[1] = hy;
        h2 pb; pb[0] = hz; pb[1] = hw;
        *(float2*)(&Qsh[row][c4*4]) = make_float2(__builtin_bit_cast(float, pa),
                                                  __builtin_bit_cast(float, pb));
        h2 la; la[0] = (_Float16)(v.x - (float)hx); la[1] = (_Float16)(v.y - (float)hy);
        h2 lb; lb[0] = (_Float16)(v.z - (float)hz); lb[1] = (_Float16)(v.w - (float)hw);
        *(float2*)(&Qsl[row][c4*4]) = make_float2(__builtin_bit_cast(float, la),
                                                  __builtin_bit_cast(float, lb));
    }
    __syncthreads();
    f16x8 aqh[8], aql[8];
    #pragma unroll
    for (int kf = 0; kf < 8; ++kf) {
        aqh[kf] = *(const f16x8*)(&Qsh[w + 4*lc][kf*32 + lg*8]);
        aql[kf] = *(const f16x8*)(&Qsl[w + 4*lc][kf*32 + lg*8]);
    }

    f32x4 cacc[16] = {};
    float rowM[4] = {-1e30f, -1e30f, -1e30f, -1e30f};
    float rowL[4] = {0.f, 0.f, 0.f, 0.f};

    int T = 2*bx + 2;
    for (int tt = 0; tt < T; ++tt) {
        int m0 = tt << 5;
        __syncthreads();
        #pragma unroll
        for (int p = 0; p < 8; ++p) {
            int i = p*256 + t;
            int row = i >> 6, c4 = i & 63;
            float4 kv = *(const float4*)(modif + ((size_t)b*1024 + m0 + row)*256 + c4*4);
            _Float16 hx = (_Float16)kv.x, hy = (_Float16)kv.y, hz = (_Float16)kv.z, hw = (_Float16)kv.w;
            h2 pa; pa[0] = hx; pa[1] = hy;
            h2 pb; pb[0] = hz; pb[1] = hw;
            *(float2*)(&Ksh[row][c4*4]) = make_float2(__builtin_bit_cast(float, pa),
                                                      __builtin_bit_cast(float, pb));
            h2 la; la[0] = (_Float16)(kv.x - (float)hx); la[1] = (_Float16)(kv.y - (float)hy);
            h2 lb; lb[0] = (_Float16)(kv.z - (float)hz); lb[1] = (_Float16)(kv.w - (float)hw);
            *(float2*)(&Ksl[row][c4*4]) = make_float2(__builtin_bit_cast(float, la),
                                                      __builtin_bit_cast(float, lb));
            float4 vv = *(const float4*)(outs + ((size_t)b*1024 + m0 + row)*256 + c4*4);
            Vt[c4*4+0][row] = (_Float16)vv.x;
            Vt[c4*4+1][row] = (_Float16)vv.y;
            Vt[c4*4+2][row] = (_Float16)vv.z;
            Vt[c4*4+3][row] = (_Float16)vv.w;
        }
        __syncthreads();
        f32x4 s0 = {0.f,0.f,0.f,0.f}, s1 = {0.f,0.f,0.f,0.f};
        #pragma unroll
        for (int kf = 0; kf < 8; ++kf) {
            f16x8 b0h = *(const f16x8*)(&Ksh[lc][kf*32 + lg*8]);
            f16x8 b0l = *(const f16x8*)(&Ksl[lc][kf*32 + lg*8]);
            f16x8 b1h = *(const f16x8*)(&Ksh[16 + lc][kf*32 + lg*8]);
            f16x8 b1l = *(const f16x8*)(&Ksl[16 + lc][kf*32 + lg*8]);
            s0 = __builtin_amdgcn_mfma_f32_16x16x32_f16(aqh[kf], b0h, s0, 0, 0, 0);
            s0 = __builtin_amdgcn_mfma_f32_16x16x32_f16(aqh[kf], b0l, s0, 0, 0, 0);
            s0 = __builtin_amdgcn_mfma_f32_16x16x32_f16(aql[kf], b0h, s0, 0, 0, 0);
            s1 = __builtin_amdgcn_mfma_f32_16x16x32_f16(aqh[kf], b1h, s1, 0, 0, 0);
            s1 = __builtin_amdgcn_mfma_f32_16x16x32_f16(aqh[kf], b1l, s1, 0, 0, 0);
            s1 = __builtin_amdgcn_mfma_f32_16x16x32_f16(aql[kf], b1h, s1, 0, 0, 0);
        }
        #pragma unroll
        for (int r = 0; r < 4; ++r) {
            int m = lg*4 + r;
            int grow = l0 + w + 4*m;
            float v0 = s0[r], v1 = s1[r];
            if (m0 + lc      >= grow) v0 = -1e30f;
            if (m0 + 16 + lc >= grow) v1 = -1e30f;
            float mx = fmaxf(v0, v1);
            mx = fmaxf(mx, __shfl_xor(mx, 1));
            mx = fmaxf(mx, __shfl_xor(mx, 2));
            mx = fmaxf(mx, __shfl_xor(mx, 4));
            mx = fmaxf(mx, __shfl_xor(mx, 8));
            float nm = fmaxf(rowM[r], mx);
            float sc, p0, p1;
            if (nm < -1e29f) { sc = 1.f; p0 = 0.f; p1 = 0.f; }
            else { sc = fexp(rowM[r] - nm); p0 = fexp(v0 - nm); p1 = fexp(v1 - nm); }
            rowM[r] = nm;
            float ts = p0 + p1;
            ts += __shfl_xor(ts, 1);
            ts += __shfl_xor(ts, 2);
            ts += __shfl_xor(ts, 4);
            ts += __shfl_xor(ts, 8);
            rowL[r] = rowL[r]*sc + ts;
            sP[w][m][lc]      = (_Float16)p0;
            sP[w][m][16 + lc] = (_Float16)p1;
            #pragma unroll
            for (int nt = 0; nt < 16; ++nt) cacc[nt][r] *= sc;
        }
        asm volatile("s_waitcnt lgkmcnt(0)" ::: "memory");
        __builtin_amdgcn_sched_barrier(0);
        f16x8 pa = *(const f16x8*)(&sP[w][lc][lg*8]);
        #pragma unroll
        for (int nt = 0; nt < 16; ++nt) {
            f16x8 bv = *(const f16x8*)(&Vt[nt*16 + lc][lg*8]);
            cacc[nt] = __builtin_amdgcn_mfma_f32_16x16x32_f16(pa, bv, cacc[nt], 0, 0, 0);
        }
    }
    #pragma unroll
    for (int r = 0; r < 4; ++r) {
        int grow = l0 + w + 4*(lg*4 + r);
        float inv = (grow == 0) ? 0.f : 1.f/rowL[r];
        #pragma unroll
        for (int nt = 0; nt < 16; ++nt)
            ctx[((size_t)b*1024 + grow)*256 + nt*16 + lc] = cacc[nt][r]*inv;
    }
}

// ---------------- final: logits + outputs ----------------
__global__ __launch_bounds__(256) void k_final(
    const float* __restrict__ h2v, const float* __restrict__ w2, const float* __restrict__ b2,
    const float* __restrict__ mask, float* __restrict__ out)
{
    int i = blockIdx.x*256 + threadIdx.x;   // < 32768
    const float4* h4 = (const float4*)(h2v + (size_t)i*256);
    const float4* w4 = (const float4*)w2;
    float a0=0,a1=0,a2=0,a3=0;
    #pragma unroll 8
    for (int k = 0; k < 64; ++k) {
        float4 h = h4[k], w = w4[k];
        a0 += h.x*w.x; a1 += h.y*w.y; a2 += h.z*w.z; a3 += h.w*w.w;
    }
    float lg = a0+a1+a2+a3 + b2[0];
    float p = sigm(lg);
    out[2*i]     = 1.0f - p;
    out[2*i + 1] = p;
    out[65536  + i] = (lg > 0.f) ? 1.0f : ((lg < 0.f) ? -1.0f : 0.0f);
    out[98304  + i] = mask[i];
    out[131072 + i] = lg;
}

extern "C" void kernel_launch(void* const* d_in, const int* in_sizes, int n_in,
                              void* d_out, int out_size, void* d_ws, size_t ws_size,
                              hipStream_t stream)
{
    const float* ne      = (const float*)d_in[0];
    const float* mask    = (const float*)d_in[1];
    const int*   trg     = (const int*)  d_in[2];
    const float* se_w0   = (const float*)d_in[3];
    const float* se_b0   = (const float*)d_in[4];
    const float* se_w1   = (const float*)d_in[5];
    const float* se_b1   = (const float*)d_in[6];
    const float* se_w2   = (const float*)d_in[7];
    const float* se_b2   = (const float*)d_in[8];
    const float* w_ih0   = (const float*)d_in[9];
    const float* w_hh0   = (const float*)d_in[10];
    const float* b_ih0   = (const float*)d_in[11];
    const float* b_hh0   = (const float*)d_in[12];
    const float* w_ih1   = (const float*)d_in[13];
    const float* w_hh1   = (const float*)d_in[14];
    const float* b_ih1   = (const float*)d_in[15];
    const float* b_hh1   = (const float*)d_in[16];
    const float* attn_w1 = (const float*)d_in[17];
    const float* attn_b1 = (const float*)d_in[18];
    const float* comb_w  = (const float*)d_in[19];
    const float* comb_b  = (const float*)d_in[20];
    const float* dec_w0  = (const float*)d_in[21];
    const float* dec_b0  = (const float*)d_in[22];
    const float* dec_w1  = (const float*)d_in[23];
    const float* dec_b1  = (const float*)d_in[24];
    const float* dec_w2  = (const float*)d_in[25];
    const float* dec_b2  = (const float*)d_in[26];

    float* W    = (float*)d_ws;
    float* sh   = W;                    // 8192
    float* o0   = W + 8192;             // [L,B,D] 8388608
    float* xp1f = W + 8396800;          // [L,B,G] f16 (6.29M float slots used)
    float* outs = W + 33562624;         // [B,L,D] 8388608
    float* modif = o0;                  // o0 dead after pipe
    float* ctx  = xp1f + 8388608;       // past f16 xp1 footprint
    float* dec  = xp1f + 16777216;      // written after pipe (flags dead by then)
    unsigned* flags = (unsigned*)(xp1f + 16777216);   // 64 words, used only during pipe
    float* h1   = o0;                   // after attention: modif dead
    float* h2b  = xp1f;                 // after dec0: xp1 dead
    float* out  = (float*)d_out;

    k_start_embed<<<32, 256, 0, stream>>>(ne, se_w0, se_b0, se_w1, se_b1, se_w2, se_b2, sh);
    k_zero<<<1, 64, 0, stream>>>(flags);
    k_pipe<<<96, 512, 0, stream>>>(w_hh0, b_hh0, w_ih0, b_ih0,
                                   w_hh1, b_hh1, w_ih1, b_ih1,
                                   trg, sh, o0, (_Float16*)xp1f, outs, flags);
    k_gemm_mfma<<<512, 256, 0, stream>>>(outs, attn_w1, attn_b1, modif, NROWS, 256, 256, 0, 0, 0, nullptr, nullptr);
    { dim3 ag(16, 32); k_attn_mfma<<<ag, 256, 0, stream>>>(outs, modif, ctx); }
    k_gemm_mfma<<<512, 256, 0, stream>>>(ctx, comb_w, comb_b, dec, NROWS, 256, 768, 2, 3, 0, outs, sh);
    k_gemm_mfma<<<512, 256, 0, stream>>>(dec, dec_w0, dec_b0, h1, NROWS, 256, 256, 1, 0, 0, nullptr, nullptr);
    k_gemm_mfma<<<512, 256, 0, stream>>>(h1, dec_w1, dec_b1, h2b, NROWS, 256, 256, 1, 0, 0, nullptr, nullptr);
    k_final<<<128, 256, 0, stream>>>(h2b, dec_w2, dec_b2, mask, out);
}

// Round 21
// 2830.707 us; speedup vs baseline: 1.2230x; 1.2230x over previous
//
#include <hip/hip_runtime.h>
#include <math.h>

// B=32, L=1024, D=256, G=768
#define NROWS 32768  // B*L

typedef float v4 __attribute__((ext_vector_type(4)));
typedef _Float16 h2 __attribute__((ext_vector_type(2)));
typedef _Float16 f16x8 __attribute__((ext_vector_type(8)));
typedef float f32x4 __attribute__((ext_vector_type(4)));

__device__ __forceinline__ float geluf(float x){ return 0.5f*x*(1.0f+erff(x*0.70710678118654752f)); }

// ---- fast transcendentals: native v_exp_f32 (exp2) + v_rcp_f32 ----
__device__ __forceinline__ float fexp2(float x){
#if __has_builtin(__builtin_amdgcn_exp2f)
    return __builtin_amdgcn_exp2f(x);
#else
    return exp2f(x);
#endif
}
__device__ __forceinline__ float frcp(float x){
#if __has_builtin(__builtin_amdgcn_rcpf)
    return __builtin_amdgcn_rcpf(x);
#else
    return 1.0f/x;
#endif
}
#define LOG2E 1.44269504088896f
__device__ __forceinline__ float fexp(float x){ return fexp2(x*LOG2E); }
__device__ __forceinline__ float sigm(float x){ return frcp(1.0f + fexp2(-LOG2E*x)); }
__device__ __forceinline__ float ftanh(float x){ return 1.0f - 2.0f*frcp(fexp2(2.0f*LOG2E*x) + 1.0f); }

__device__ __forceinline__ float dot2(h2 a, h2 b, float c){
#if __has_builtin(__builtin_amdgcn_fdot2)
    return __builtin_amdgcn_fdot2(a, b, c, false);
#else
    return c + (float)a.x*(float)b.x + (float)a.y*(float)b.y;
#endif
}
__device__ __forceinline__ h2 cvt2(float2 a){ return h2{(_Float16)a.x, (_Float16)a.y}; }

// barrier that does NOT drain vmcnt: LDS visibility only (R12/R16-passing form).
__device__ __forceinline__ void wg_barrier(){
    asm volatile("s_waitcnt lgkmcnt(0)" ::: "memory");
    __builtin_amdgcn_s_barrier();
    __builtin_amdgcn_sched_barrier(0);
}

// ---------------- start embed: sh[b,d] ----------------
__global__ __launch_bounds__(256) void k_start_embed(
    const float* __restrict__ ne, const float* __restrict__ w0, const float* __restrict__ b0,
    const float* __restrict__ w1, const float* __restrict__ b1,
    const float* __restrict__ w2, const float* __restrict__ b2,
    float* __restrict__ sh)
{
    __shared__ __align__(16) float encL[1024];
    __shared__ __align__(16) float g1[256];
    __shared__ __align__(16) float g2[256];
    int b = blockIdx.x, t = threadIdx.x;
    for (int i = t; i < 1024; i += 256) encL[i] = ne[b*1024 + i];
    __syncthreads();
    const float4* wr = (const float4*)(w0 + (size_t)t*1024);
    const float4* e4 = (const float4*)encL;
    float a0=0,a1=0,a2=0,a3=0;
    #pragma unroll 8
    for (int k = 0; k < 256; ++k){ float4 w = wr[k], e = e4[k];
        a0 += w.x*e.x; a1 += w.y*e.y; a2 += w.z*e.z; a3 += w.w*e.w; }
    float t1 = a0+a1+a2+a3 + b0[t];
    float res = t1;
    g1[t] = geluf(t1);
    __syncthreads();
    const float4* w1r = (const float4*)(w1 + (size_t)t*256);
    const float4* g14 = (const float4*)g1;
    a0=a1=a2=a3=0.f;
    #pragma unroll 8
    for (int k = 0; k < 64; ++k){ float4 w = w1r[k], e = g14[k];
        a0 += w.x*e.x; a1 += w.y*e.y; a2 += w.z*e.z; a3 += w.w*e.w; }
    g2[t] = geluf(a0+a1+a2+a3 + b1[t]);
    __syncthreads();
    const float4* w2r = (const float4*)(w2 + (size_t)t*256);
    const float4* g24 = (const float4*)g2;
    a0=a1=a2=a3=0.f;
    #pragma unroll 8
    for (int k = 0; k < 64; ++k){ float4 w = w2r[k], e = g24[k];
        a0 += w.x*e.x; a1 += w.y*e.y; a2 += w.z*e.z; a3 += w.w*e.w; }
    sh[b*256 + t] = a0+a1+a2+a3 + b2[t] + res;
}

// permuted f16 index within an hbuf row for hidden dim:
// dim = (hi:2)(mid:3)(lo:3) -> idx = mid*32 + hi*8 + lo  (bijective).
__device__ __forceinline__ int hperm(int dim){
    return ((dim >> 3) & 7)*32 + ((dim >> 6) << 3) + (dim & 7);
}

// ---------------- GRU scan v12 (R16/R19-passing; xp1 f16) ----------------
// Pipe-bound (R17/R18 probes): v_dot2_f32_f16 and v_pk_fma_f16 both issue at
// ~4cy (quarter-rate); floor = 1536 cy/step; this structure runs ~2300 cy/step
// (barrier+LDS dependency tail) = best measured 1173 us. R20's producer-
// consumer pipeline regressed (cross-XCD fence cost) -> this stays final.
template<int LAYER>
__global__ __launch_bounds__(512) void k_gru3(
    const float* __restrict__ w_hh, const float* __restrict__ b_hh,
    const float* __restrict__ w_ih0, const float* __restrict__ b_ih0,
    const _Float16* __restrict__ xp1,
    const int*   __restrict__ trg,
    const float* __restrict__ sh,
    float* __restrict__ out)
{
    __shared__ __align__(16) float4 wNs[8192];      // 128KB: [kk 0..15][t 0..511]
    __shared__ __align__(16) _Float16 hbuf[2][256];
    __shared__ __align__(16) float bitL[1024];
    int b = blockIdx.x, t = threadIdx.x;
    int d = t >> 1, half = t & 1;

    if (LAYER == 0) {
        #pragma unroll
        for (int i = 0; i < 2; ++i) {
            int idx = t + i*512;
            bitL[idx] = (idx == 0) ? 1.0f : (float)trg[b*1024 + idx - 1];
        }
    }

    // --- wN K-half of row d -> LDS (f16 packed), once; linear, conflict-free ---
    {
        const float2* src = (const float2*)(w_hh + (size_t)(512 + d)*256 + half*128);
        #pragma unroll
        for (int kk = 0; kk < 16; ++kk) {
            h2 p0 = cvt2(src[kk*4+0]), p1 = cvt2(src[kk*4+1]);
            h2 p2 = cvt2(src[kk*4+2]), p3 = cvt2(src[kk*4+3]);
            float4 v;
            v.x = __builtin_bit_cast(float, p0); v.y = __builtin_bit_cast(float, p1);
            v.z = __builtin_bit_cast(float, p2); v.w = __builtin_bit_cast(float, p3);
            wNs[kk*512 + t] = v;
        }
    }
    // --- wR, wZ K-halves -> registers (f16 packed) ---
    h2 wR[64], wZ[64];
    {
        const float2* wr = (const float2*)(w_hh + (size_t)d*256       + half*128);
        const float2* wz = (const float2*)(w_hh + (size_t)(d+256)*256 + half*128);
        #pragma unroll
        for (int k = 0; k < 64; ++k) { wR[k] = cvt2(wr[k]); wZ[k] = cvt2(wz[k]); }
    }
    float bhr = b_hh[d], bhz = b_hh[256 + d], bhn = b_hh[512 + d];
    float wir=0.f, wiz=0.f, win=0.f, bir=0.f, biz=0.f, bin=0.f;
    if (LAYER == 0) {
        wir = w_ih0[d]; wiz = w_ih0[256 + d]; win = w_ih0[512 + d];
        bir = b_ih0[d]; biz = b_ih0[256 + d]; bin = b_ih0[512 + d];
    }

    float hreg = sh[b*256 + d];
    if (half == 0) hbuf[0][hperm(d)] = (_Float16)hreg;

    float xr = 0.f, xz = 0.f, xn = 0.f;
    if (LAYER == 1) {
        size_t base = (size_t)b*768;
        xr = (float)xp1[base + d]; xz = (float)xp1[base + 256 + d]; xn = (float)xp1[base + 512 + d];
    }
    __syncthreads();

    for (int l = 0; l < 1024; ++l) {
        const float4* hb4 = (const float4*)(&hbuf[l & 1][0]);
        float ar = 0.f, az = 0.f, an = 0.f;
        #pragma unroll
        for (int kk = 0; kk < 16; ++kk) {
            float4 hv = hb4[(kk & 7)*4 + half*2 + (kk >> 3)];  // wave 2-addr broadcast
            float4 wv = wNs[kk*512 + t];                       // conflict-free private
            h2 h0 = __builtin_bit_cast(h2, hv.x);
            h2 h1 = __builtin_bit_cast(h2, hv.y);
            h2 hc = __builtin_bit_cast(h2, hv.z);
            h2 h3 = __builtin_bit_cast(h2, hv.w);
            ar = dot2(wR[4*kk+0], h0, ar); ar = dot2(wR[4*kk+1], h1, ar);
            ar = dot2(wR[4*kk+2], hc, ar); ar = dot2(wR[4*kk+3], h3, ar);
            az = dot2(wZ[4*kk+0], h0, az); az = dot2(wZ[4*kk+1], h1, az);
            az = dot2(wZ[4*kk+2], hc, az); az = dot2(wZ[4*kk+3], h3, az);
            an = dot2(__builtin_bit_cast(h2, wv.x), h0, an);
            an = dot2(__builtin_bit_cast(h2, wv.y), h1, an);
            an = dot2(__builtin_bit_cast(h2, wv.z), hc, an);
            an = dot2(__builtin_bit_cast(h2, wv.w), h3, an);
        }
        ar += __shfl_xor(ar, 1);
        az += __shfl_xor(az, 1);
        an += __shfl_xor(an, 1);
        if (LAYER == 0) {
            float bit = bitL[l];
            xr = bir + bit*wir; xz = biz + bit*wiz; xn = bin + bit*win;
        }
        float r = sigm(xr + ar + bhr);
        float z = sigm(xz + az + bhz);
        float n = ftanh(xn + r*(an + bhn));
        hreg = (1.0f - z)*n + z*hreg;
        if (half == 0) {
            hbuf[(l + 1) & 1][hperm(d)] = (_Float16)hreg;
        } else {
            size_t oidx = (LAYER == 0) ? (((size_t)l*32 + b)*256 + d)
                                       : (((size_t)b*1024 + l)*256 + d);
            out[oidx] = hreg;
        }
        if (LAYER == 1) {
            int ln = (l < 1023) ? (l + 1) : 1023;
            size_t base = ((size_t)ln*32 + b)*768;
            xr = (float)xp1[base + d]; xz = (float)xp1[base + 256 + d]; xn = (float)xp1[base + 512 + d];
        }
        wg_barrier();
    }
}

// ---------------- f16 MFMA GEMM (R9-verified; optional f16 output) ----------------
__global__ __launch_bounds__(256, 3) void k_gemm_mfma(
    const float* __restrict__ A, const float* __restrict__ B,
    const float* __restrict__ bias, float* __restrict__ C,
    int M, int N, int K, int act, int aMode, int outHalf,
    const float* __restrict__ A1, const float* __restrict__ A2)
{
    __shared__ __align__(16) _Float16 As[128][40];
    __shared__ __align__(16) _Float16 Bs[128][40];
    int nbn = N >> 7;
    int bx = blockIdx.x % nbn, by = blockIdx.x / nbn;
    int m0 = by << 7, n0 = bx << 7;
    int t = threadIdx.x;
    int w = t >> 6, l = t & 63;
    int wm = w >> 1, wn = w & 1;
    int lc = l & 15, lg = l >> 4;
    f32x4 acc[4][4] = {};
    for (int kt = 0; kt < K; kt += 32) {
        __syncthreads();
        #pragma unroll
        for (int p = 0; p < 4; ++p) {
            int slot = t + p*256;            // 1024 slots: (m, kc)
            int m = slot >> 3, kc = slot & 7;
            int gk = kt + kc*4;
            float4 va;
            if (aMode == 0) {
                va = *(const float4*)(A + (size_t)(m0+m)*K + gk);
            } else {
                int part = gk >> 8, kk = gk & 255;
                const float* P = (part == 0) ? A : ((part == 1) ? A1 : A2);
                int row = (part == 2) ? ((m0+m) >> 10) : (m0+m);
                va = *(const float4*)(P + (size_t)row*256 + kk);
            }
            h2 pa; pa[0] = (_Float16)va.x; pa[1] = (_Float16)va.y;
            h2 pb; pb[0] = (_Float16)va.z; pb[1] = (_Float16)va.w;
            *(float2*)(&As[m][kc*4]) = make_float2(__builtin_bit_cast(float, pa),
                                                   __builtin_bit_cast(float, pb));
            float4 vb = *(const float4*)(B + (size_t)(n0+m)*K + gk);
            h2 qa; qa[0] = (_Float16)vb.x; qa[1] = (_Float16)vb.y;
            h2 qb; qb[0] = (_Float16)vb.z; qb[1] = (_Float16)vb.w;
            *(float2*)(&Bs[m][kc*4]) = make_float2(__builtin_bit_cast(float, qa),
                                                   __builtin_bit_cast(float, qb));
        }
        __syncthreads();
        f16x8 af[4], bf[4];
        #pragma unroll
        for (int mt = 0; mt < 4; ++mt)
            af[mt] = *(const f16x8*)(&As[wm*64 + mt*16 + lc][lg*8]);
        #pragma unroll
        for (int nt = 0; nt < 4; ++nt)
            bf[nt] = *(const f16x8*)(&Bs[wn*64 + nt*16 + lc][lg*8]);
        #pragma unroll
        for (int mt = 0; mt < 4; ++mt)
            #pragma unroll
            for (int nt = 0; nt < 4; ++nt)
                acc[mt][nt] = __builtin_amdgcn_mfma_f32_16x16x32_f16(af[mt], bf[nt], acc[mt][nt], 0, 0, 0);
    }
    #pragma unroll
    for (int nt = 0; nt < 4; ++nt) {
        int col = n0 + wn*64 + nt*16 + lc;
        float bv = bias[col];
        #pragma unroll
        for (int mt = 0; mt < 4; ++mt) {
            int rbase = m0 + wm*64 + mt*16 + lg*4;
            #pragma unroll
            for (int r = 0; r < 4; ++r) {
                float v = acc[mt][nt][r] + bv;
                if (act == 1) v = geluf(v);
                else if (act == 2) v = ftanh(v);
                if (outHalf) ((_Float16*)C)[(size_t)(rbase + r)*N + col] = (_Float16)v;
                else         C[(size_t)(rbase + r)*N + col] = v;
            }
        }
    }
}

// ---------------- MFMA flash attention v5: hi/lo QK, f16 PV (R17-R19-passing) ----------------
__global__ __launch_bounds__(256) void k_attn_mfma(
    const float* __restrict__ outs, const float* __restrict__ modif, float* __restrict__ ctx)
{
    __shared__ __align__(16) _Float16 Qsh[64][264];
    __shared__ __align__(16) _Float16 Qsl[64][264];
    __shared__ __align__(16) _Float16 Ksh[32][264];
    __shared__ __align__(16) _Float16 Ksl[32][264];
    __shared__ __align__(16) _Float16 Vt[256][40];
    __shared__ __align__(16) _Float16 sP[4][16][40];
    int b = blockIdx.y, bx = blockIdx.x, l0 = bx << 6, t = threadIdx.x;
    int w = t >> 6, l = t & 63;
    int lc = l & 15, lg = l >> 4;

    #pragma unroll
    for (int p = 0; p < 16; ++p) {
        int i = p*256 + t;
        int row = i >> 6, c4 = i & 63;
        float4 v = *(const float4*)(outs + ((size_t)b*1024 + l0 + row)*256 + c4*4);
        _Float16 hx = (_Float16)v.x, hy = (_Float16)v.y, hz = (_Float16)v.z, hw = (_Float16)v.w;
        h2 pa; pa[0] = hx; pa[1] = hy;
        h2 pb; pb[0] = hz; pb[1] = hw;
        *(float2*)(&Qsh[row][c4*4]) = make_float2(__builtin_bit_cast(float, pa),
                                                  __builtin_bit_cast(float, pb));
        h2 la; la[0] = (_Float16)(v.x - (float)hx); la[1] = (_Float16)(v.y - (float)hy);
        h2 lb; lb[0] = (_Float16)(v.z - (float)hz); lb[1] = (_Float16)(v.w - (float)hw);
        *(float2*)(&Qsl[row][c4*4]) = make_float2(__builtin_bit_cast(float, la),
                                                  __builtin_bit_cast(float, lb));
    }
    __syncthreads();
    f16x8 aqh[8], aql[8];
    #pragma unroll
    for (int kf = 0; kf < 8; ++kf) {
        aqh[kf] = *(const f16x8*)(&Qsh[w + 4*lc][kf*32 + lg*8]);
        aql[kf] = *(const f16x8*)(&Qsl[w + 4*lc][kf*32 + lg*8]);
    }

    f32x4 cacc[16] = {};
    float rowM[4] = {-1e30f, -1e30f, -1e30f, -1e30f};
    float rowL[4] = {0.f, 0.f, 0.f, 0.f};

    int T = 2*bx + 2;
    for (int tt = 0; tt < T; ++tt) {
        int m0 = tt << 5;
        __syncthreads();
        #pragma unroll
        for (int p = 0; p < 8; ++p) {
            int i = p*256 + t;
            int row = i >> 6, c4 = i & 63;
            float4 kv = *(const float4*)(modif + ((size_t)b*1024 + m0 + row)*256 + c4*4);
            _Float16 hx = (_Float16)kv.x, hy = (_Float16)kv.y, hz = (_Float16)kv.z, hw = (_Float16)kv.w;
            h2 pa; pa[0] = hx; pa[1] = hy;
            h2 pb; pb[0] = hz; pb[1] = hw;
            *(float2*)(&Ksh[row][c4*4]) = make_float2(__builtin_bit_cast(float, pa),
                                                      __builtin_bit_cast(float, pb));
            h2 la; la[0] = (_Float16)(kv.x - (float)hx); la[1] = (_Float16)(kv.y - (float)hy);
            h2 lb; lb[0] = (_Float16)(kv.z - (float)hz); lb[1] = (_Float16)(kv.w - (float)hw);
            *(float2*)(&Ksl[row][c4*4]) = make_float2(__builtin_bit_cast(float, la),
                                                      __builtin_bit_cast(float, lb));
            float4 vv = *(const float4*)(outs + ((size_t)b*1024 + m0 + row)*256 + c4*4);
            Vt[c4*4+0][row] = (_Float16)vv.x;
            Vt[c4*4+1][row] = (_Float16)vv.y;
            Vt[c4*4+2][row] = (_Float16)vv.z;
            Vt[c4*4+3][row] = (_Float16)vv.w;
        }
        __syncthreads();
        f32x4 s0 = {0.f,0.f,0.f,0.f}, s1 = {0.f,0.f,0.f,0.f};
        #pragma unroll
        for (int kf = 0; kf < 8; ++kf) {
            f16x8 b0h = *(const f16x8*)(&Ksh[lc][kf*32 + lg*8]);
            f16x8 b0l = *(const f16x8*)(&Ksl[lc][kf*32 + lg*8]);
            f16x8 b1h = *(const f16x8*)(&Ksh[16 + lc][kf*32 + lg*8]);
            f16x8 b1l = *(const f16x8*)(&Ksl[16 + lc][kf*32 + lg*8]);
            s0 = __builtin_amdgcn_mfma_f32_16x16x32_f16(aqh[kf], b0h, s0, 0, 0, 0);
            s0 = __builtin_amdgcn_mfma_f32_16x16x32_f16(aqh[kf], b0l, s0, 0, 0, 0);
            s0 = __builtin_amdgcn_mfma_f32_16x16x32_f16(aql[kf], b0h, s0, 0, 0, 0);
            s1 = __builtin_amdgcn_mfma_f32_16x16x32_f16(aqh[kf], b1h, s1, 0, 0, 0);
            s1 = __builtin_amdgcn_mfma_f32_16x16x32_f16(aqh[kf], b1l, s1, 0, 0, 0);
            s1 = __builtin_amdgcn_mfma_f32_16x16x32_f16(aql[kf], b1h, s1, 0, 0, 0);
        }
        #pragma unroll
        for (int r = 0; r < 4; ++r) {
            int m = lg*4 + r;
            int grow = l0 + w + 4*m;
            float v0 = s0[r], v1 = s1[r];
            if (m0 + lc      >= grow) v0 = -1e30f;
            if (m0 + 16 + lc >= grow) v1 = -1e30f;
            float mx = fmaxf(v0, v1);
            mx = fmaxf(mx, __shfl_xor(mx, 1));
            mx = fmaxf(mx, __shfl_xor(mx, 2));
            mx = fmaxf(mx, __shfl_xor(mx, 4));
            mx = fmaxf(mx, __shfl_xor(mx, 8));
            float nm = fmaxf(rowM[r], mx);
            float sc, p0, p1;
            if (nm < -1e29f) { sc = 1.f; p0 = 0.f; p1 = 0.f; }
            else { sc = fexp(rowM[r] - nm); p0 = fexp(v0 - nm); p1 = fexp(v1 - nm); }
            rowM[r] = nm;
            float ts = p0 + p1;
            ts += __shfl_xor(ts, 1);
            ts += __shfl_xor(ts, 2);
            ts += __shfl_xor(ts, 4);
            ts += __shfl_xor(ts, 8);
            rowL[r] = rowL[r]*sc + ts;
            sP[w][m][lc]      = (_Float16)p0;
            sP[w][m][16 + lc] = (_Float16)p1;
            #pragma unroll
            for (int nt = 0; nt < 16; ++nt) cacc[nt][r] *= sc;
        }
        asm volatile("s_waitcnt lgkmcnt(0)" ::: "memory");
        __builtin_amdgcn_sched_barrier(0);
        f16x8 pa = *(const f16x8*)(&sP[w][lc][lg*8]);
        #pragma unroll
        for (int nt = 0; nt < 16; ++nt) {
            f16x8 bv = *(const f16x8*)(&Vt[nt*16 + lc][lg*8]);
            cacc[nt] = __builtin_amdgcn_mfma_f32_16x16x32_f16(pa, bv, cacc[nt], 0, 0, 0);
        }
    }
    #pragma unroll
    for (int r = 0; r < 4; ++r) {
        int grow = l0 + w + 4*(lg*4 + r);
        float inv = (grow == 0) ? 0.f : 1.f/rowL[r];
        #pragma unroll
        for (int nt = 0; nt < 16; ++nt)
            ctx[((size_t)b*1024 + grow)*256 + nt*16 + lc] = cacc[nt][r]*inv;
    }
}

// ---------------- final: logits + outputs ----------------
__global__ __launch_bounds__(256) void k_final(
    const float* __restrict__ h2v, const float* __restrict__ w2, const float* __restrict__ b2,
    const float* __restrict__ mask, float* __restrict__ out)
{
    int i = blockIdx.x*256 + threadIdx.x;   // < 32768
    const float4* h4 = (const float4*)(h2v + (size_t)i*256);
    const float4* w4 = (const float4*)w2;
    float a0=0,a1=0,a2=0,a3=0;
    #pragma unroll 8
    for (int k = 0; k < 64; ++k) {
        float4 h = h4[k], w = w4[k];
        a0 += h.x*w.x; a1 += h.y*w.y; a2 += h.z*w.z; a3 += h.w*w.w;
    }
    float lg = a0+a1+a2+a3 + b2[0];
    float p = sigm(lg);
    out[2*i]     = 1.0f - p;
    out[2*i + 1] = p;
    out[65536  + i] = (lg > 0.f) ? 1.0f : ((lg < 0.f) ? -1.0f : 0.0f);
    out[98304  + i] = mask[i];
    out[131072 + i] = lg;
}

extern "C" void kernel_launch(void* const* d_in, const int* in_sizes, int n_in,
                              void* d_out, int out_size, void* d_ws, size_t ws_size,
                              hipStream_t stream)
{
    const float* ne      = (const float*)d_in[0];
    const float* mask    = (const float*)d_in[1];
    const int*   trg     = (const int*)  d_in[2];
    const float* se_w0   = (const float*)d_in[3];
    const float* se_b0   = (const float*)d_in[4];
    const float* se_w1   = (const float*)d_in[5];
    const float* se_b1   = (const float*)d_in[6];
    const float* se_w2   = (const float*)d_in[7];
    const float* se_b2   = (const float*)d_in[8];
    const float* w_ih0   = (const float*)d_in[9];
    const float* w_hh0   = (const float*)d_in[10];
    const float* b_ih0   = (const float*)d_in[11];
    const float* b_hh0   = (const float*)d_in[12];
    const float* w_ih1   = (const float*)d_in[13];
    const float* w_hh1   = (const float*)d_in[14];
    const float* b_ih1   = (const float*)d_in[15];
    const float* b_hh1   = (const float*)d_in[16];
    const float* attn_w1 = (const float*)d_in[17];
    const float* attn_b1 = (const float*)d_in[18];
    const float* comb_w  = (const float*)d_in[19];
    const float* comb_b  = (const float*)d_in[20];
    const float* dec_w0  = (const float*)d_in[21];
    const float* dec_b0  = (const float*)d_in[22];
    const float* dec_w1  = (const float*)d_in[23];
    const float* dec_b1  = (const float*)d_in[24];
    const float* dec_w2  = (const float*)d_in[25];
    const float* dec_b2  = (const float*)d_in[26];

    float* W    = (float*)d_ws;
    float* sh   = W;                    // 8192
    float* o0   = W + 8192;             // [L,B,D] 8388608
    float* xp1f = W + 8396800;          // [L,B,G] f16 (6.29M float slots used)
    float* outs = W + 33562624;         // [B,L,D] 8388608
    float* modif = o0;                  // o0 dead after xp1 GEMM
    float* ctx  = xp1f + 8388608;       // past f16 xp1 footprint (no overlap)
    float* dec  = xp1f + 16777216;
    float* h1   = o0;                   // after attention: modif dead
    float* h2b  = xp1f;                 // after dec0: xp1 dead
    float* out  = (float*)d_out;

    k_start_embed<<<32, 256, 0, stream>>>(ne, se_w0, se_b0, se_w1, se_b1, se_w2, se_b2, sh);
    k_gru3<0><<<32, 512, 0, stream>>>(w_hh0, b_hh0, w_ih0, b_ih0, nullptr, trg, sh, o0);
    k_gemm_mfma<<<1536, 256, 0, stream>>>(o0, w_ih1, b_ih1, xp1f, NROWS, 768, 256, 0, 0, 1, nullptr, nullptr);
    k_gru3<1><<<32, 512, 0, stream>>>(w_hh1, b_hh1, nullptr, nullptr, (const _Float16*)xp1f, trg, sh, outs);
    k_gemm_mfma<<<512, 256, 0, stream>>>(outs, attn_w1, attn_b1, modif, NROWS, 256, 256, 0, 0, 0, nullptr, nullptr);
    { dim3 ag(16, 32); k_attn_mfma<<<ag, 256, 0, stream>>>(outs, modif, ctx); }
    k_gemm_mfma<<<512, 256, 0, stream>>>(ctx, comb_w, comb_b, dec, NROWS, 256, 768, 2, 3, 0, outs, sh);
    k_gemm_mfma<<<512, 256, 0, stream>>>(dec, dec_w0, dec_b0, h1, NROWS, 256, 256, 1, 0, 0, nullptr, nullptr);
    k_gemm_mfma<<<512, 256, 0, stream>>>(h1, dec_w1, dec_b1, h2b, NROWS, 256, 256, 1, 0, 0, nullptr, nullptr);
    k_final<<<128, 256, 0, stream>>>(h2b, dec_w2, dec_b2, mask, out);
}

// Round 22
// 2750.382 us; speedup vs baseline: 1.2587x; 1.0292x over previous
//
#include <hip/hip_runtime.h>
#include <math.h>

// B=32, L=1024, D=256, G=768
#define NROWS 32768  // B*L

typedef float v4 __attribute__((ext_vector_type(4)));
typedef _Float16 h2 __attribute__((ext_vector_type(2)));
typedef _Float16 f16x8 __attribute__((ext_vector_type(8)));
typedef float f32x4 __attribute__((ext_vector_type(4)));

__device__ __forceinline__ float geluf(float x){ return 0.5f*x*(1.0f+erff(x*0.70710678118654752f)); }

// ---- fast transcendentals: native v_exp_f32 (exp2) + v_rcp_f32 ----
__device__ __forceinline__ float fexp2(float x){
#if __has_builtin(__builtin_amdgcn_exp2f)
    return __builtin_amdgcn_exp2f(x);
#else
    return exp2f(x);
#endif
}
__device__ __forceinline__ float frcp(float x){
#if __has_builtin(__builtin_amdgcn_rcpf)
    return __builtin_amdgcn_rcpf(x);
#else
    return 1.0f/x;
#endif
}
#define LOG2E 1.44269504088896f
__device__ __forceinline__ float fexp(float x){ return fexp2(x*LOG2E); }
__device__ __forceinline__ float sigm(float x){ return frcp(1.0f + fexp2(-LOG2E*x)); }
__device__ __forceinline__ float ftanh(float x){ return 1.0f - 2.0f*frcp(fexp2(2.0f*LOG2E*x) + 1.0f); }

__device__ __forceinline__ float dot2(h2 a, h2 b, float c){
#if __has_builtin(__builtin_amdgcn_fdot2)
    return __builtin_amdgcn_fdot2(a, b, c, false);
#else
    return c + (float)a.x*(float)b.x + (float)a.y*(float)b.y;
#endif
}
__device__ __forceinline__ h2 cvt2(float2 a){ return h2{(_Float16)a.x, (_Float16)a.y}; }

// barrier that does NOT drain vmcnt: LDS visibility only (R12/R16-passing form).
__device__ __forceinline__ void wg_barrier(){
    asm volatile("s_waitcnt lgkmcnt(0)" ::: "memory");
    __builtin_amdgcn_s_barrier();
    __builtin_amdgcn_sched_barrier(0);
}

// ---------------- start embed: sh[b,d] ----------------
__global__ __launch_bounds__(256) void k_start_embed(
    const float* __restrict__ ne, const float* __restrict__ w0, const float* __restrict__ b0,
    const float* __restrict__ w1, const float* __restrict__ b1,
    const float* __restrict__ w2, const float* __restrict__ b2,
    float* __restrict__ sh)
{
    __shared__ __align__(16) float encL[1024];
    __shared__ __align__(16) float g1[256];
    __shared__ __align__(16) float g2[256];
    int b = blockIdx.x, t = threadIdx.x;
    for (int i = t; i < 1024; i += 256) encL[i] = ne[b*1024 + i];
    __syncthreads();
    const float4* wr = (const float4*)(w0 + (size_t)t*1024);
    const float4* e4 = (const float4*)encL;
    float a0=0,a1=0,a2=0,a3=0;
    #pragma unroll 8
    for (int k = 0; k < 256; ++k){ float4 w = wr[k], e = e4[k];
        a0 += w.x*e.x; a1 += w.y*e.y; a2 += w.z*e.z; a3 += w.w*e.w; }
    float t1 = a0+a1+a2+a3 + b0[t];
    float res = t1;
    g1[t] = geluf(t1);
    __syncthreads();
    const float4* w1r = (const float4*)(w1 + (size_t)t*256);
    const float4* g14 = (const float4*)g1;
    a0=a1=a2=a3=0.f;
    #pragma unroll 8
    for (int k = 0; k < 64; ++k){ float4 w = w1r[k], e = g14[k];
        a0 += w.x*e.x; a1 += w.y*e.y; a2 += w.z*e.z; a3 += w.w*e.w; }
    g2[t] = geluf(a0+a1+a2+a3 + b1[t]);
    __syncthreads();
    const float4* w2r = (const float4*)(w2 + (size_t)t*256);
    const float4* g24 = (const float4*)g2;
    a0=a1=a2=a3=0.f;
    #pragma unroll 8
    for (int k = 0; k < 64; ++k){ float4 w = w2r[k], e = g24[k];
        a0 += w.x*e.x; a1 += w.y*e.y; a2 += w.z*e.z; a3 += w.w*e.w; }
    sh[b*256 + t] = a0+a1+a2+a3 + b2[t] + res;
}

// permuted f16 index within an hbuf row for hidden dim:
// dim = (hi:2)(mid:3)(lo:3) -> idx = mid*32 + hi*8 + lo  (bijective).
__device__ __forceinline__ int hperm(int dim){
    return ((dim >> 3) & 7)*32 + ((dim >> 6) << 3) + (dim & 7);
}

// ---------------- GRU scan v12 (R16/R19/R21-passing; xp1 f16) ----------------
template<int LAYER>
__global__ __launch_bounds__(512) void k_gru3(
    const float* __restrict__ w_hh, const float* __restrict__ b_hh,
    const float* __restrict__ w_ih0, const float* __restrict__ b_ih0,
    const _Float16* __restrict__ xp1,
    const int*   __restrict__ trg,
    const float* __restrict__ sh,
    float* __restrict__ out)
{
    __shared__ __align__(16) float4 wNs[8192];      // 128KB: [kk 0..15][t 0..511]
    __shared__ __align__(16) _Float16 hbuf[2][256];
    __shared__ __align__(16) float bitL[1024];
    int b = blockIdx.x, t = threadIdx.x;
    int d = t >> 1, half = t & 1;

    if (LAYER == 0) {
        #pragma unroll
        for (int i = 0; i < 2; ++i) {
            int idx = t + i*512;
            bitL[idx] = (idx == 0) ? 1.0f : (float)trg[b*1024 + idx - 1];
        }
    }

    {
        const float2* src = (const float2*)(w_hh + (size_t)(512 + d)*256 + half*128);
        #pragma unroll
        for (int kk = 0; kk < 16; ++kk) {
            h2 p0 = cvt2(src[kk*4+0]), p1 = cvt2(src[kk*4+1]);
            h2 p2 = cvt2(src[kk*4+2]), p3 = cvt2(src[kk*4+3]);
            float4 v;
            v.x = __builtin_bit_cast(float, p0); v.y = __builtin_bit_cast(float, p1);
            v.z = __builtin_bit_cast(float, p2); v.w = __builtin_bit_cast(float, p3);
            wNs[kk*512 + t] = v;
        }
    }
    h2 wR[64], wZ[64];
    {
        const float2* wr = (const float2*)(w_hh + (size_t)d*256       + half*128);
        const float2* wz = (const float2*)(w_hh + (size_t)(d+256)*256 + half*128);
        #pragma unroll
        for (int k = 0; k < 64; ++k) { wR[k] = cvt2(wr[k]); wZ[k] = cvt2(wz[k]); }
    }
    float bhr = b_hh[d], bhz = b_hh[256 + d], bhn = b_hh[512 + d];
    float wir=0.f, wiz=0.f, win=0.f, bir=0.f, biz=0.f, bin=0.f;
    if (LAYER == 0) {
        wir = w_ih0[d]; wiz = w_ih0[256 + d]; win = w_ih0[512 + d];
        bir = b_ih0[d]; biz = b_ih0[256 + d]; bin = b_ih0[512 + d];
    }

    float hreg = sh[b*256 + d];
    if (half == 0) hbuf[0][hperm(d)] = (_Float16)hreg;

    float xr = 0.f, xz = 0.f, xn = 0.f;
    if (LAYER == 1) {
        size_t base = (size_t)b*768;
        xr = (float)xp1[base + d]; xz = (float)xp1[base + 256 + d]; xn = (float)xp1[base + 512 + d];
    }
    __syncthreads();

    for (int l = 0; l < 1024; ++l) {
        const float4* hb4 = (const float4*)(&hbuf[l & 1][0]);
        float ar = 0.f, az = 0.f, an = 0.f;
        #pragma unroll
        for (int kk = 0; kk < 16; ++kk) {
            float4 hv = hb4[(kk & 7)*4 + half*2 + (kk >> 3)];  // wave 2-addr broadcast
            float4 wv = wNs[kk*512 + t];                       // conflict-free private
            h2 h0 = __builtin_bit_cast(h2, hv.x);
            h2 h1 = __builtin_bit_cast(h2, hv.y);
            h2 hc = __builtin_bit_cast(h2, hv.z);
            h2 h3 = __builtin_bit_cast(h2, hv.w);
            ar = dot2(wR[4*kk+0], h0, ar); ar = dot2(wR[4*kk+1], h1, ar);
            ar = dot2(wR[4*kk+2], hc, ar); ar = dot2(wR[4*kk+3], h3, ar);
            az = dot2(wZ[4*kk+0], h0, az); az = dot2(wZ[4*kk+1], h1, az);
            az = dot2(wZ[4*kk+2], hc, az); az = dot2(wZ[4*kk+3], h3, az);
            an = dot2(__builtin_bit_cast(h2, wv.x), h0, an);
            an = dot2(__builtin_bit_cast(h2, wv.y), h1, an);
            an = dot2(__builtin_bit_cast(h2, wv.z), hc, an);
            an = dot2(__builtin_bit_cast(h2, wv.w), h3, an);
        }
        ar += __shfl_xor(ar, 1);
        az += __shfl_xor(az, 1);
        an += __shfl_xor(an, 1);
        if (LAYER == 0) {
            float bit = bitL[l];
            xr = bir + bit*wir; xz = biz + bit*wiz; xn = bin + bit*win;
        }
        float r = sigm(xr + ar + bhr);
        float z = sigm(xz + az + bhz);
        float n = ftanh(xn + r*(an + bhn));
        hreg = (1.0f - z)*n + z*hreg;
        if (half == 0) {
            hbuf[(l + 1) & 1][hperm(d)] = (_Float16)hreg;
        } else {
            size_t oidx = (LAYER == 0) ? (((size_t)l*32 + b)*256 + d)
                                       : (((size_t)b*1024 + l)*256 + d);
            out[oidx] = hreg;
        }
        if (LAYER == 1) {
            int ln = (l < 1023) ? (l + 1) : 1023;
            size_t base = ((size_t)ln*32 + b)*768;
            xr = (float)xp1[base + d]; xz = (float)xp1[base + 256 + d]; xn = (float)xp1[base + 512 + d];
        }
        wg_barrier();
    }
}

// ---------------- f16 MFMA GEMM (R9-verified; optional f16 output) ----------------
__global__ __launch_bounds__(256, 3) void k_gemm_mfma(
    const float* __restrict__ A, const float* __restrict__ B,
    const float* __restrict__ bias, float* __restrict__ C,
    int M, int N, int K, int act, int aMode, int outHalf,
    const float* __restrict__ A1, const float* __restrict__ A2)
{
    __shared__ __align__(16) _Float16 As[128][40];
    __shared__ __align__(16) _Float16 Bs[128][40];
    int nbn = N >> 7;
    int bx = blockIdx.x % nbn, by = blockIdx.x / nbn;
    int m0 = by << 7, n0 = bx << 7;
    int t = threadIdx.x;
    int w = t >> 6, l = t & 63;
    int wm = w >> 1, wn = w & 1;
    int lc = l & 15, lg = l >> 4;
    f32x4 acc[4][4] = {};
    for (int kt = 0; kt < K; kt += 32) {
        __syncthreads();
        #pragma unroll
        for (int p = 0; p < 4; ++p) {
            int slot = t + p*256;            // 1024 slots: (m, kc)
            int m = slot >> 3, kc = slot & 7;
            int gk = kt + kc*4;
            float4 va;
            if (aMode == 0) {
                va = *(const float4*)(A + (size_t)(m0+m)*K + gk);
            } else {
                int part = gk >> 8, kk = gk & 255;
                const float* P = (part == 0) ? A : ((part == 1) ? A1 : A2);
                int row = (part == 2) ? ((m0+m) >> 10) : (m0+m);
                va = *(const float4*)(P + (size_t)row*256 + kk);
            }
            h2 pa; pa[0] = (_Float16)va.x; pa[1] = (_Float16)va.y;
            h2 pb; pb[0] = (_Float16)va.z; pb[1] = (_Float16)va.w;
            *(float2*)(&As[m][kc*4]) = make_float2(__builtin_bit_cast(float, pa),
                                                   __builtin_bit_cast(float, pb));
            float4 vb = *(const float4*)(B + (size_t)(n0+m)*K + gk);
            h2 qa; qa[0] = (_Float16)vb.x; qa[1] = (_Float16)vb.y;
            h2 qb; qb[0] = (_Float16)vb.z; qb[1] = (_Float16)vb.w;
            *(float2*)(&Bs[m][kc*4]) = make_float2(__builtin_bit_cast(float, qa),
                                                   __builtin_bit_cast(float, qb));
        }
        __syncthreads();
        f16x8 af[4], bf[4];
        #pragma unroll
        for (int mt = 0; mt < 4; ++mt)
            af[mt] = *(const f16x8*)(&As[wm*64 + mt*16 + lc][lg*8]);
        #pragma unroll
        for (int nt = 0; nt < 4; ++nt)
            bf[nt] = *(const f16x8*)(&Bs[wn*64 + nt*16 + lc][lg*8]);
        #pragma unroll
        for (int mt = 0; mt < 4; ++mt)
            #pragma unroll
            for (int nt = 0; nt < 4; ++nt)
                acc[mt][nt] = __builtin_amdgcn_mfma_f32_16x16x32_f16(af[mt], bf[nt], acc[mt][nt], 0, 0, 0);
    }
    #pragma unroll
    for (int nt = 0; nt < 4; ++nt) {
        int col = n0 + wn*64 + nt*16 + lc;
        float bv = bias[col];
        #pragma unroll
        for (int mt = 0; mt < 4; ++mt) {
            int rbase = m0 + wm*64 + mt*16 + lg*4;
            #pragma unroll
            for (int r = 0; r < 4; ++r) {
                float v = acc[mt][nt][r] + bv;
                if (act == 1) v = geluf(v);
                else if (act == 2) v = ftanh(v);
                if (outHalf) ((_Float16*)C)[(size_t)(rbase + r)*N + col] = (_Float16)v;
                else         C[(size_t)(rbase + r)*N + col] = v;
            }
        }
    }
}

// ---------------- MFMA flash attention v6: pure f16 QK + f16 PV ----------------
// R13's f16-QK "precision failure" was actually the half-sized grid (found
// R16); pure f16 QK was never tested unconfounded. Error budget: S rel ~1e-3
// -> P rel ~1e-2 -> logits few e-3 through 0.05-scale comb weights, inside
// the 2e-2 threshold. Drops 32 of 48 QK MFMAs/tile + Qsl/Ksl staging.
__global__ __launch_bounds__(256) void k_attn_mfma(
    const float* __restrict__ outs, const float* __restrict__ modif, float* __restrict__ ctx)
{
    __shared__ __align__(16) _Float16 Qs[64][264];
    __shared__ __align__(16) _Float16 Ks[32][264];
    __shared__ __align__(16) _Float16 Vt[256][40];
    __shared__ __align__(16) _Float16 sP[4][16][40];
    int b = blockIdx.y, bx = blockIdx.x, l0 = bx << 6, t = threadIdx.x;
    int w = t >> 6, l = t & 63;
    int lc = l & 15, lg = l >> 4;

    #pragma unroll
    for (int p = 0; p < 16; ++p) {
        int i = p*256 + t;
        int row = i >> 6, c4 = i & 63;
        float4 v = *(const float4*)(outs + ((size_t)b*1024 + l0 + row)*256 + c4*4);
        h2 pa; pa[0] = (_Float16)v.x; pa[1] = (_Float16)v.y;
        h2 pb; pb[0] = (_Float16)v.z; pb[1] = (_Float16)v.w;
        *(float2*)(&Qs[row][c4*4]) = make_float2(__builtin_bit_cast(float, pa),
                                                 __builtin_bit_cast(float, pb));
    }
    __syncthreads();
    f16x8 aq[8];
    #pragma unroll
    for (int kf = 0; kf < 8; ++kf)
        aq[kf] = *(const f16x8*)(&Qs[w + 4*lc][kf*32 + lg*8]);

    f32x4 cacc[16] = {};
    float rowM[4] = {-1e30f, -1e30f, -1e30f, -1e30f};
    float rowL[4] = {0.f, 0.f, 0.f, 0.f};

    int T = 2*bx + 2;
    for (int tt = 0; tt < T; ++tt) {
        int m0 = tt << 5;
        __syncthreads();
        #pragma unroll
        for (int p = 0; p < 8; ++p) {
            int i = p*256 + t;
            int row = i >> 6, c4 = i & 63;
            float4 kv = *(const float4*)(modif + ((size_t)b*1024 + m0 + row)*256 + c4*4);
            h2 pa; pa[0] = (_Float16)kv.x; pa[1] = (_Float16)kv.y;
            h2 pb; pb[0] = (_Float16)kv.z; pb[1] = (_Float16)kv.w;
            *(float2*)(&Ks[row][c4*4]) = make_float2(__builtin_bit_cast(float, pa),
                                                     __builtin_bit_cast(float, pb));
            float4 vv = *(const float4*)(outs + ((size_t)b*1024 + m0 + row)*256 + c4*4);
            Vt[c4*4+0][row] = (_Float16)vv.x;
            Vt[c4*4+1][row] = (_Float16)vv.y;
            Vt[c4*4+2][row] = (_Float16)vv.z;
            Vt[c4*4+3][row] = (_Float16)vv.w;
        }
        __syncthreads();
        f32x4 s0 = {0.f,0.f,0.f,0.f}, s1 = {0.f,0.f,0.f,0.f};
        #pragma unroll
        for (int kf = 0; kf < 8; ++kf) {
            f16x8 b0 = *(const f16x8*)(&Ks[lc][kf*32 + lg*8]);
            f16x8 b1 = *(const f16x8*)(&Ks[16 + lc][kf*32 + lg*8]);
            s0 = __builtin_amdgcn_mfma_f32_16x16x32_f16(aq[kf], b0, s0, 0, 0, 0);
            s1 = __builtin_amdgcn_mfma_f32_16x16x32_f16(aq[kf], b1, s1, 0, 0, 0);
        }
        #pragma unroll
        for (int r = 0; r < 4; ++r) {
            int m = lg*4 + r;
            int grow = l0 + w + 4*m;
            float v0 = s0[r], v1 = s1[r];
            if (m0 + lc      >= grow) v0 = -1e30f;
            if (m0 + 16 + lc >= grow) v1 = -1e30f;
            float mx = fmaxf(v0, v1);
            mx = fmaxf(mx, __shfl_xor(mx, 1));
            mx = fmaxf(mx, __shfl_xor(mx, 2));
            mx = fmaxf(mx, __shfl_xor(mx, 4));
            mx = fmaxf(mx, __shfl_xor(mx, 8));
            float nm = fmaxf(rowM[r], mx);
            float sc, p0, p1;
            if (nm < -1e29f) { sc = 1.f; p0 = 0.f; p1 = 0.f; }
            else { sc = fexp(rowM[r] - nm); p0 = fexp(v0 - nm); p1 = fexp(v1 - nm); }
            rowM[r] = nm;
            float ts = p0 + p1;
            ts += __shfl_xor(ts, 1);
            ts += __shfl_xor(ts, 2);
            ts += __shfl_xor(ts, 4);
            ts += __shfl_xor(ts, 8);
            rowL[r] = rowL[r]*sc + ts;
            sP[w][m][lc]      = (_Float16)p0;
            sP[w][m][16 + lc] = (_Float16)p1;
            #pragma unroll
            for (int nt = 0; nt < 16; ++nt) cacc[nt][r] *= sc;
        }
        asm volatile("s_waitcnt lgkmcnt(0)" ::: "memory");
        __builtin_amdgcn_sched_barrier(0);
        f16x8 pa = *(const f16x8*)(&sP[w][lc][lg*8]);
        #pragma unroll
        for (int nt = 0; nt < 16; ++nt) {
            f16x8 bv = *(const f16x8*)(&Vt[nt*16 + lc][lg*8]);
            cacc[nt] = __builtin_amdgcn_mfma_f32_16x16x32_f16(pa, bv, cacc[nt], 0, 0, 0);
        }
    }
    #pragma unroll
    for (int r = 0; r < 4; ++r) {
        int grow = l0 + w + 4*(lg*4 + r);
        float inv = (grow == 0) ? 0.f : 1.f/rowL[r];
        #pragma unroll
        for (int nt = 0; nt < 16; ++nt)
            ctx[((size_t)b*1024 + grow)*256 + nt*16 + lc] = cacc[nt][r]*inv;
    }
}

// ---------------- final: logits + outputs ----------------
__global__ __launch_bounds__(256) void k_final(
    const float* __restrict__ h2v, const float* __restrict__ w2, const float* __restrict__ b2,
    const float* __restrict__ mask, float* __restrict__ out)
{
    int i = blockIdx.x*256 + threadIdx.x;   // < 32768
    const float4* h4 = (const float4*)(h2v + (size_t)i*256);
    const float4* w4 = (const float4*)w2;
    float a0=0,a1=0,a2=0,a3=0;
    #pragma unroll 8
    for (int k = 0; k < 64; ++k) {
        float4 h = h4[k], w = w4[k];
        a0 += h.x*w.x; a1 += h.y*w.y; a2 += h.z*w.z; a3 += h.w*w.w;
    }
    float lg = a0+a1+a2+a3 + b2[0];
    float p = sigm(lg);
    out[2*i]     = 1.0f - p;
    out[2*i + 1] = p;
    out[65536  + i] = (lg > 0.f) ? 1.0f : ((lg < 0.f) ? -1.0f : 0.0f);
    out[98304  + i] = mask[i];
    out[131072 + i] = lg;
}

extern "C" void kernel_launch(void* const* d_in, const int* in_sizes, int n_in,
                              void* d_out, int out_size, void* d_ws, size_t ws_size,
                              hipStream_t stream)
{
    const float* ne      = (const float*)d_in[0];
    const float* mask    = (const float*)d_in[1];
    const int*   trg     = (const int*)  d_in[2];
    const float* se_w0   = (const float*)d_in[3];
    const float* se_b0   = (const float*)d_in[4];
    const float* se_w1   = (const float*)d_in[5];
    const float* se_b1   = (const float*)d_in[6];
    const float* se_w2   = (const float*)d_in[7];
    const float* se_b2   = (const float*)d_in[8];
    const float* w_ih0   = (const float*)d_in[9];
    const float* w_hh0   = (const float*)d_in[10];
    const float* b_ih0   = (const float*)d_in[11];
    const float* b_hh0   = (const float*)d_in[12];
    const float* w_ih1   = (const float*)d_in[13];
    const float* w_hh1   = (const float*)d_in[14];
    const float* b_ih1   = (const float*)d_in[15];
    const float* b_hh1   = (const float*)d_in[16];
    const float* attn_w1 = (const float*)d_in[17];
    const float* attn_b1 = (const float*)d_in[18];
    const float* comb_w  = (const float*)d_in[19];
    const float* comb_b  = (const float*)d_in[20];
    const float* dec_w0  = (const float*)d_in[21];
    const float* dec_b0  = (const float*)d_in[22];
    const float* dec_w1  = (const float*)d_in[23];
    const float* dec_b1  = (const float*)d_in[24];
    const float* dec_w2  = (const float*)d_in[25];
    const float* dec_b2  = (const float*)d_in[26];

    float* W    = (float*)d_ws;
    float* sh   = W;                    // 8192
    float* o0   = W + 8192;             // [L,B,D] 8388608
    float* xp1f = W + 8396800;          // [L,B,G] f16 (6.29M float slots used)
    float* outs = W + 33562624;         // [B,L,D] 8388608
    float* modif = o0;                  // o0 dead after xp1 GEMM
    float* ctx  = xp1f + 8388608;       // past f16 xp1 footprint (no overlap)
    float* dec  = xp1f + 16777216;
    float* h1   = o0;                   // after attention: modif dead
    float* h2b  = xp1f;                 // after dec0: xp1 dead
    float* out  = (float*)d_out;

    k_start_embed<<<32, 256, 0, stream>>>(ne, se_w0, se_b0, se_w1, se_b1, se_w2, se_b2, sh);
    k_gru3<0><<<32, 512, 0, stream>>>(w_hh0, b_hh0, w_ih0, b_ih0, nullptr, trg, sh, o0);
    k_gemm_mfma<<<1536, 256, 0, stream>>>(o0, w_ih1, b_ih1, xp1f, NROWS, 768, 256, 0, 0, 1, nullptr, nullptr);
    k_gru3<1><<<32, 512, 0, stream>>>(w_hh1, b_hh1, nullptr, nullptr, (const _Float16*)xp1f, trg, sh, outs);
    k_gemm_mfma<<<512, 256, 0, stream>>>(outs, attn_w1, attn_b1, modif, NROWS, 256, 256, 0, 0, 0, nullptr, nullptr);
    { dim3 ag(16, 32); k_attn_mfma<<<ag, 256, 0, stream>>>(outs, modif, ctx); }
    k_gemm_mfma<<<512, 256, 0, stream>>>(ctx, comb_w, comb_b, dec, NROWS, 256, 768, 2, 3, 0, outs, sh);
    k_gemm_mfma<<<512, 256, 0, stream>>>(dec, dec_w0, dec_b0, h1, NROWS, 256, 256, 1, 0, 0, nullptr, nullptr);
    k_gemm_mfma<<<512, 256, 0, stream>>>(h1, dec_w1, dec_b1, h2b, NROWS, 256, 256, 1, 0, 0, nullptr, nullptr);
    k_final<<<128, 256, 0, stream>>>(h2b, dec_w2, dec_b2, mask, out);
}